// Round 10
// baseline (462.082 us; speedup 1.0000x reference)
//
#include <hip/hip_runtime.h>
#include <hip/hip_bf16.h>

typedef __bf16 bf16;
typedef __bf16 bf16x4 __attribute__((ext_vector_type(4)));
typedef __bf16 bf16x8 __attribute__((ext_vector_type(8)));
typedef float f32x4 __attribute__((ext_vector_type(4)));
typedef float f32x16 __attribute__((ext_vector_type(16)));
typedef unsigned u32x4 __attribute__((ext_vector_type(4)));

#define MFMA16(a, b, c) __builtin_amdgcn_mfma_f32_16x16x32_bf16((a), (b), (c), 0, 0, 0)
#define MFMA32(a, b, c) __builtin_amdgcn_mfma_f32_32x32x16_bf16((a), (b), (c), 0, 0, 0)

// XCD-chunked block swizzle (nblk % 8 == 0): each XCD gets a contiguous chunk.
__device__ __forceinline__ int xcd_swizzle(int bid, int nblk) {
  const int per = nblk >> 3;
  return (bid & 7) * per + (bid >> 3);
}

__device__ __forceinline__ unsigned pack2bf(float a, float b) {
  const unsigned short ua = __builtin_bit_cast(unsigned short, (bf16)a);
  const unsigned short ub = __builtin_bit_cast(unsigned short, (bf16)b);
  return (unsigned)ua | ((unsigned)ub << 16);
}

// ---------------- GEMM machinery (128x128 tile, BK=64, 2-phase) ------------
template <typename T> struct StageRegs;
template <> struct StageRegs<float> { float4 lo[4], hi[4]; };
template <> struct StageRegs<bf16> { bf16x8 v[4]; };

template <typename T>
__device__ __forceinline__ void stage_issue(StageRegs<T>& r, const T* base,
                                            int rowstride, int brc, int k0,
                                            int tid) {
#pragma unroll
  for (int i = 0; i < 4; ++i) {
    const int c = i * 256 + tid;
    const int row = c >> 3, lin = c & 7;
    const T* p = base + (size_t)(brc + row) * rowstride + k0 + lin * 8;
    if constexpr (sizeof(T) == 4) {
      r.lo[i] = *reinterpret_cast<const float4*>(p);
      r.hi[i] = *reinterpret_cast<const float4*>(p + 4);
    } else {
      r.v[i] = *reinterpret_cast<const bf16x8*>(p);
    }
  }
}

template <typename T>
__device__ __forceinline__ void stage_write(const StageRegs<T>& r, bf16* sm,
                                            int tid) {
#pragma unroll
  for (int i = 0; i < 4; ++i) {
    const int c = i * 256 + tid;
    const int row = c >> 3, lin = c & 7;
    const int slot = lin ^ (row & 7);
    bf16x8 v;
    if constexpr (sizeof(T) == 4) {
      const float4 a = r.lo[i], b = r.hi[i];
      v[0] = (bf16)a.x; v[1] = (bf16)a.y; v[2] = (bf16)a.z; v[3] = (bf16)a.w;
      v[4] = (bf16)b.x; v[5] = (bf16)b.y; v[6] = (bf16)b.z; v[7] = (bf16)b.w;
    } else {
      v = r.v[i];
    }
    *reinterpret_cast<bf16x8*>(sm + row * 64 + slot * 8) = v;
  }
}

// Shared main-loop: accumulates A[brow:+128] @ W[bcol:+128]^T over K=1024.
template <typename TA>
__device__ __forceinline__ void gemm_core(const TA* A, const float* W,
                                          int brow, int bcol, int tid, int wm,
                                          int wn, int l15, int l4,
                                          bf16 (*Asm)[8192], bf16 (*Bsm)[8192],
                                          f32x4 (&acc)[4][4]) {
  StageRegs<TA> ra;
  StageRegs<float> rb;
  stage_issue(ra, A, 1024, brow, 0, tid);
  stage_issue(rb, W, 1024, bcol, 0, tid);
  int p = 0;
  for (int t = 0; t < 16; ++t) {
    stage_write(ra, Asm[p], tid);
    stage_write(rb, Bsm[p], tid);
    if (t + 1 < 16) {
      stage_issue(ra, A, 1024, brow, (t + 1) << 6, tid);
      stage_issue(rb, W, 1024, bcol, (t + 1) << 6, tid);
    }
    __syncthreads();
#pragma unroll
    for (int kk = 0; kk < 2; ++kk) {
      bf16x8 af[4], bfr[4];
#pragma unroll
      for (int m = 0; m < 4; ++m) {
        const int row = wm + m * 16 + l15;
        const int slot = (kk * 4 + l4) ^ (row & 7);
        af[m] = *reinterpret_cast<const bf16x8*>(Asm[p] + row * 64 + slot * 8);
      }
#pragma unroll
      for (int n = 0; n < 4; ++n) {
        const int row = wn + n * 16 + l15;
        const int slot = (kk * 4 + l4) ^ (row & 7);
        bfr[n] = *reinterpret_cast<const bf16x8*>(Bsm[p] + row * 64 + slot * 8);
      }
      __builtin_amdgcn_s_setprio(1);
#pragma unroll
      for (int m = 0; m < 4; ++m)
#pragma unroll
        for (int n = 0; n < 4; ++n)
          acc[m][n] = MFMA16(af[m], bfr[n], acc[m][n]);
      __builtin_amdgcn_s_setprio(0);
    }
    __syncthreads();
    p ^= 1;
  }
}

// Fused QKV projection. seg 0 -> Qws (x log2e/8), seg 1 -> Kws,
// seg 2 -> Vt written TRANSPOSED (replaces the transpose kernel).
__global__ __launch_bounds__(256, 2) void qkv_gemm_kernel(
    const float* __restrict__ query, const float* __restrict__ key,
    const float* __restrict__ value, const float* __restrict__ wq,
    const float* __restrict__ wk, const float* __restrict__ wv,
    const float* __restrict__ bq, const float* __restrict__ bk,
    const float* __restrict__ bv, bf16* __restrict__ Qws,
    bf16* __restrict__ Kws, bf16* __restrict__ Vt, float qscale) {
  __shared__ bf16 Asm[2][128 * 64];
  __shared__ bf16 Bsm[2][128 * 64];
  const int tid = threadIdx.x;
  const int lane = tid & 63;
  const int wid = tid >> 6;
  const int l15 = lane & 15;
  const int l4 = lane >> 4;
  const int bid = xcd_swizzle(blockIdx.x, 1536);
  const int seg = bid / 512;
  const int inner = bid % 512;
  const int brow = (inner >> 3) << 7;
  const int bcol = (inner & 7) << 7;
  const int wm = (wid >> 1) << 6;
  const int wn = (wid & 1) << 6;

  const float* A = seg == 0 ? query : (seg == 1 ? key : value);
  const float* W = seg == 0 ? wq : (seg == 1 ? wk : wv);
  const float* bias = seg == 0 ? bq : (seg == 1 ? bk : bv);

  f32x4 acc[4][4] = {};
  gemm_core(A, W, brow, bcol, tid, wm, wn, l15, l4, Asm, Bsm, acc);

  const int r0 = brow + wm + l4 * 4;
  const int c0 = bcol + wn + l15;
  if (seg < 2) {
    bf16* C = seg == 0 ? Qws : Kws;
    const float cs = seg == 0 ? qscale : 1.0f;
#pragma unroll
    for (int n = 0; n < 4; ++n) {
      const float bvv = bias[c0 + n * 16];
#pragma unroll
      for (int m = 0; m < 4; ++m)
#pragma unroll
        for (int r = 0; r < 4; ++r)
          C[(size_t)(r0 + m * 16 + r) * 1024 + (c0 + n * 16)] =
              (bf16)((acc[m][n][r] + bvv) * cs);
    }
  } else {
    // Vt[b*1024 + col][s] = V[row][col]; rows r=0..3 are s-consecutive.
#pragma unroll
    for (int n = 0; n < 4; ++n) {
      const float bvv = bias[c0 + n * 16];
      const int col = c0 + n * 16;
#pragma unroll
      for (int m = 0; m < 4; ++m) {
        const int row = r0 + m * 16;
        const int bq_ = row >> 11;
        const int srow = row & 2047;
        bf16x4 pk4;
#pragma unroll
        for (int r = 0; r < 4; ++r) pk4[r] = (bf16)(acc[m][n][r] + bvv);
        *reinterpret_cast<bf16x4*>(
            &Vt[(size_t)(bq_ * 1024 + col) * 2048 + srow]) = pk4;
      }
    }
  }
}

// Output projection GEMM (bf16 ctx @ fp32 wo^T + bo -> fp32 out).
__global__ __launch_bounds__(256, 2) void out_gemm_kernel(
    const bf16* __restrict__ A, const float* __restrict__ W,
    const float* __restrict__ bias, float* __restrict__ C) {
  __shared__ bf16 Asm[2][128 * 64];
  __shared__ bf16 Bsm[2][128 * 64];
  const int tid = threadIdx.x;
  const int lane = tid & 63;
  const int wid = tid >> 6;
  const int l15 = lane & 15;
  const int l4 = lane >> 4;
  const int bid = xcd_swizzle(blockIdx.x, 512);
  const int brow = (bid >> 3) << 7;
  const int bcol = (bid & 7) << 7;
  const int wm = (wid >> 1) << 6;
  const int wn = (wid & 1) << 6;

  f32x4 acc[4][4] = {};
  gemm_core(A, W, brow, bcol, tid, wm, wn, l15, l4, Asm, Bsm, acc);

  const int r0 = brow + wm + l4 * 4;
  const int c0 = bcol + wn + l15;
#pragma unroll
  for (int n = 0; n < 4; ++n) {
    const float bvv = bias[c0 + n * 16];
#pragma unroll
    for (int m = 0; m < 4; ++m)
#pragma unroll
      for (int r = 0; r < 4; ++r)
        C[(size_t)(r0 + m * 16 + r) * 1024 + (c0 + n * 16)] =
            acc[m][n][r] + bvv;
  }
}

// ---------------- Flash attention: no LDS, no barriers, cache-direct -------
// Block = (b, h, 128 q); 4 fully independent waves x 32 q. K/V slices per
// (b,h) = 512 KB (L2-fits) and mask 1 MB/block (L2/L3) -> staging was pure
// overhead (common-mistake #7); all operands read directly from cache with
// per-lane running pointers + imm offsets. pi (swap k-bits 2,3) is baked into
// the per-lane K row address so P stays lane-local for PV (zero exchange).
// Loop = 64 half-tiles of 32 k; NO cross-lane ops inside the loop (partner
// lrow sum deferred to one end-of-loop shfl). Q pre-scaled by log2e/8; mask
// enters as the QK MFMA C-initializer (x log2e). Fixed-shift softmax (exact).
__global__ __launch_bounds__(256, 2) void attn_kernel(
    const bf16* __restrict__ Q, const bf16* __restrict__ Kt,
    const bf16* __restrict__ Vt, const float* __restrict__ mask,
    bf16* __restrict__ ctx) {
  const int lid = xcd_swizzle(blockIdx.x, 1024);
  const int h = lid & 15;
  const int qb = (lid >> 4) & 15;
  const int b = lid >> 8;
  const int tid = threadIdx.x;
  const int lane = tid & 63;
  const int wid = tid >> 6;
  const int l31 = lane & 31;
  const int h5 = lane >> 5;
  const int qbase = qb * 128 + wid * 32;
  const int pil = (l31 & 0x13) | ((l31 & 4) << 1) | ((l31 & 8) >> 1);

  // Q B-frags: qf[c] = Q[qbase+l31][16c + 8h5 + j] (pre-scaled by log2e/8)
  bf16x8 qf[4];
#pragma unroll
  for (int c = 0; c < 4; ++c)
    qf[c] = *reinterpret_cast<const bf16x8*>(
        &Q[(size_t)(b * 2048 + qbase + l31) * 1024 + h * 64 + c * 16 + h5 * 8]);

  f32x16 o[2] = {};  // D rows q=(reg&3)+8*(reg>>2)+4h5, col dsub*32+l31
  float lrow = 0.f;
  const float LOG2E = 1.44269504088896f;

  // Running per-lane pointers (advance by constants each half-tile).
  const bf16* kp = Kt + ((size_t)b * 2048 + pil) * 1024 + h * 64 + h5 * 8;
  const bf16* vp0 = Vt + ((size_t)(b * 16 + h) * 64 + l31) * 2048 + h5 * 8;
  const bf16* vp1 = vp0 + (size_t)32 * 2048;
  const float* mp = mask + (size_t)b * 2048 * 2048 +
                    (size_t)(qbase + l31) * 2048 + h5 * 8;

  for (int t = 0; t < 64; ++t) {
    // 12 loads, imm offsets off running pointers
    bf16x8 kf[4];
#pragma unroll
    for (int c = 0; c < 4; ++c)
      kf[c] = *reinterpret_cast<const bf16x8*>(kp + c * 16);
    f32x4 mr[4];
#pragma unroll
    for (int g = 0; g < 4; ++g)
      mr[g] = *reinterpret_cast<const f32x4*>(mp + (g >> 1) * 16 + (g & 1) * 4);
    bf16x8 vf[2][2];
#pragma unroll
    for (int cc = 0; cc < 2; ++cc) {
      vf[cc][0] = *reinterpret_cast<const bf16x8*>(vp0 + cc * 16);
      vf[cc][1] = *reinterpret_cast<const bf16x8*>(vp1 + cc * 16);
    }
    kp += 32 * 1024;
    vp0 += 32;
    vp1 += 32;
    mp += 32;

    // S^T*log2e + mask*log2e (C-init); lane q=l31 holds k-set it needs for PV
    f32x16 sf;
#pragma unroll
    for (int g = 0; g < 4; ++g)
#pragma unroll
      for (int r = 0; r < 4; ++r) sf[g * 4 + r] = mr[g][r] * LOG2E;
    __builtin_amdgcn_s_setprio(1);
#pragma unroll
    for (int c = 0; c < 4; ++c) sf = MFMA32(kf[c], qf[c], sf);
    __builtin_amdgcn_s_setprio(0);

    // P = exp2(sf) -> bf16 pairs, lane-local (pi made them PV-ordered)
    unsigned pk[4][2];
#pragma unroll
    for (int g = 0; g < 4; ++g) {
      const float p0 = __builtin_exp2f(sf[g * 4 + 0]);
      const float p1 = __builtin_exp2f(sf[g * 4 + 1]);
      const float p2 = __builtin_exp2f(sf[g * 4 + 2]);
      const float p3 = __builtin_exp2f(sf[g * 4 + 3]);
      lrow += (p0 + p1) + (p2 + p3);
      pk[g][0] = pack2bf(p0, p1);
      pk[g][1] = pack2bf(p2, p3);
    }

    // PV: A-frag = 4 lane-local u32s per chunk
    __builtin_amdgcn_s_setprio(1);
#pragma unroll
    for (int cc = 0; cc < 2; ++cc) {
      const u32x4 uu = {pk[2 * cc][0], pk[2 * cc][1], pk[2 * cc + 1][0],
                        pk[2 * cc + 1][1]};
      const bf16x8 pa = __builtin_bit_cast(bf16x8, uu);
      o[0] = MFMA32(pa, vf[cc][0], o[0]);
      o[1] = MFMA32(pa, vf[cc][1], o[1]);
    }
    __builtin_amdgcn_s_setprio(0);
  }

  // Partner lane (l^32) holds the other half of each row's sum.
  lrow += __shfl_xor(lrow, 32, 64);
  const float linv = __builtin_amdgcn_rcpf(lrow);
#pragma unroll
  for (int reg = 0; reg < 16; ++reg) {
    const int qr = (reg & 3) + 8 * (reg >> 2) + 4 * h5;
    const float li = __shfl(linv, qr, 64);
    const int q = qbase + qr;
#pragma unroll
    for (int dsub = 0; dsub < 2; ++dsub) {
      ctx[(size_t)(b * 2048 + q) * 1024 + h * 64 + dsub * 32 + l31] =
          (bf16)(o[dsub][reg] * li);
    }
  }
}

extern "C" void kernel_launch(void* const* d_in, const int* in_sizes, int n_in,
                              void* d_out, int out_size, void* d_ws,
                              size_t ws_size, hipStream_t stream) {
  const float* key = (const float*)d_in[0];
  const float* query = (const float*)d_in[1];
  const float* value = (const float*)d_in[2];
  const float* mask = (const float*)d_in[3];
  const float* wq = (const float*)d_in[4];
  const float* bq = (const float*)d_in[5];
  const float* wk = (const float*)d_in[6];
  const float* bk = (const float*)d_in[7];
  const float* wv = (const float*)d_in[8];
  const float* bv = (const float*)d_in[9];
  const float* wo = (const float*)d_in[10];
  const float* bo = (const float*)d_in[11];
  float* out = (float*)d_out;

  const size_t NBSH = (size_t)4 * 2048 * 1024;
  bf16* Qws = (bf16*)d_ws;   // Q (pre-scaled by log2e/8), later ctx in place
  bf16* Kws = Qws + NBSH;
  bf16* Vt = Kws + NBSH;     // total ws use: 50.3 MB

  const dim3 blk(256);
  qkv_gemm_kernel<<<1536, blk, 0, stream>>>(query, key, value, wq, wk, wv, bq,
                                            bk, bv, Qws, Kws, Vt,
                                            0.18033688011112f);
  attn_kernel<<<1024, blk, 0, stream>>>(Qws, Kws, Vt, mask, Qws);
  out_gemm_kernel<<<512, blk, 0, stream>>>(Qws, wo, bo, out);
}

// Round 11
// 295.817 us; speedup vs baseline: 1.5621x; 1.5621x over previous
//
#include <hip/hip_runtime.h>
#include <hip/hip_bf16.h>

typedef __bf16 bf16;
typedef __bf16 bf16x4 __attribute__((ext_vector_type(4)));
typedef __bf16 bf16x8 __attribute__((ext_vector_type(8)));
typedef float f32x4 __attribute__((ext_vector_type(4)));
typedef float f32x16 __attribute__((ext_vector_type(16)));
typedef unsigned u32x4 __attribute__((ext_vector_type(4)));

#define MFMA16(a, b, c) __builtin_amdgcn_mfma_f32_16x16x32_bf16((a), (b), (c), 0, 0, 0)
#define MFMA32(a, b, c) __builtin_amdgcn_mfma_f32_32x32x16_bf16((a), (b), (c), 0, 0, 0)

// XCD-chunked block swizzle (nblk % 8 == 0): each XCD gets a contiguous chunk.
__device__ __forceinline__ int xcd_swizzle(int bid, int nblk) {
  const int per = nblk >> 3;
  return (bid & 7) * per + (bid >> 3);
}

__device__ __forceinline__ void gload_lds16(const bf16* g, bf16* lds) {
  __builtin_amdgcn_global_load_lds(
      (const __attribute__((address_space(1))) void*)g,
      (__attribute__((address_space(3))) void*)lds, 16, 0, 0);
}

__device__ __forceinline__ unsigned pack2bf(float a, float b) {
  const unsigned short ua = __builtin_bit_cast(unsigned short, (bf16)a);
  const unsigned short ub = __builtin_bit_cast(unsigned short, (bf16)b);
  return (unsigned)ua | ((unsigned)ub << 16);
}

// ---------------- GEMM machinery (128x128 tile, BK=64, 2-phase) ------------
template <typename T> struct StageRegs;
template <> struct StageRegs<float> { float4 lo[4], hi[4]; };
template <> struct StageRegs<bf16> { bf16x8 v[4]; };

template <typename T>
__device__ __forceinline__ void stage_issue(StageRegs<T>& r, const T* base,
                                            int rowstride, int brc, int k0,
                                            int tid) {
#pragma unroll
  for (int i = 0; i < 4; ++i) {
    const int c = i * 256 + tid;
    const int row = c >> 3, lin = c & 7;
    const T* p = base + (size_t)(brc + row) * rowstride + k0 + lin * 8;
    if constexpr (sizeof(T) == 4) {
      r.lo[i] = *reinterpret_cast<const float4*>(p);
      r.hi[i] = *reinterpret_cast<const float4*>(p + 4);
    } else {
      r.v[i] = *reinterpret_cast<const bf16x8*>(p);
    }
  }
}

template <typename T>
__device__ __forceinline__ void stage_write(const StageRegs<T>& r, bf16* sm,
                                            int tid) {
#pragma unroll
  for (int i = 0; i < 4; ++i) {
    const int c = i * 256 + tid;
    const int row = c >> 3, lin = c & 7;
    const int slot = lin ^ (row & 7);
    bf16x8 v;
    if constexpr (sizeof(T) == 4) {
      const float4 a = r.lo[i], b = r.hi[i];
      v[0] = (bf16)a.x; v[1] = (bf16)a.y; v[2] = (bf16)a.z; v[3] = (bf16)a.w;
      v[4] = (bf16)b.x; v[5] = (bf16)b.y; v[6] = (bf16)b.z; v[7] = (bf16)b.w;
    } else {
      v = r.v[i];
    }
    *reinterpret_cast<bf16x8*>(sm + row * 64 + slot * 8) = v;
  }
}

// Shared main-loop: accumulates A[brow:+128] @ W[bcol:+128]^T over K=1024.
template <typename TA>
__device__ __forceinline__ void gemm_core(const TA* A, const float* W,
                                          int brow, int bcol, int tid, int wm,
                                          int wn, int l15, int l4,
                                          bf16 (*Asm)[8192], bf16 (*Bsm)[8192],
                                          f32x4 (&acc)[4][4]) {
  StageRegs<TA> ra;
  StageRegs<float> rb;
  stage_issue(ra, A, 1024, brow, 0, tid);
  stage_issue(rb, W, 1024, bcol, 0, tid);
  int p = 0;
  for (int t = 0; t < 16; ++t) {
    stage_write(ra, Asm[p], tid);
    stage_write(rb, Bsm[p], tid);
    if (t + 1 < 16) {
      stage_issue(ra, A, 1024, brow, (t + 1) << 6, tid);
      stage_issue(rb, W, 1024, bcol, (t + 1) << 6, tid);
    }
    __syncthreads();
#pragma unroll
    for (int kk = 0; kk < 2; ++kk) {
      bf16x8 af[4], bfr[4];
#pragma unroll
      for (int m = 0; m < 4; ++m) {
        const int row = wm + m * 16 + l15;
        const int slot = (kk * 4 + l4) ^ (row & 7);
        af[m] = *reinterpret_cast<const bf16x8*>(Asm[p] + row * 64 + slot * 8);
      }
#pragma unroll
      for (int n = 0; n < 4; ++n) {
        const int row = wn + n * 16 + l15;
        const int slot = (kk * 4 + l4) ^ (row & 7);
        bfr[n] = *reinterpret_cast<const bf16x8*>(Bsm[p] + row * 64 + slot * 8);
      }
      __builtin_amdgcn_s_setprio(1);
#pragma unroll
      for (int m = 0; m < 4; ++m)
#pragma unroll
        for (int n = 0; n < 4; ++n)
          acc[m][n] = MFMA16(af[m], bfr[n], acc[m][n]);
      __builtin_amdgcn_s_setprio(0);
    }
    __syncthreads();
    p ^= 1;
  }
}

// Fused QKV projection. seg 0 -> Qws (x log2e/8), seg 1 -> Kws,
// seg 2 -> Vt written TRANSPOSED (replaces the transpose kernel).
__global__ __launch_bounds__(256, 2) void qkv_gemm_kernel(
    const float* __restrict__ query, const float* __restrict__ key,
    const float* __restrict__ value, const float* __restrict__ wq,
    const float* __restrict__ wk, const float* __restrict__ wv,
    const float* __restrict__ bq, const float* __restrict__ bk,
    const float* __restrict__ bv, bf16* __restrict__ Qws,
    bf16* __restrict__ Kws, bf16* __restrict__ Vt, float qscale) {
  __shared__ bf16 Asm[2][128 * 64];
  __shared__ bf16 Bsm[2][128 * 64];
  const int tid = threadIdx.x;
  const int lane = tid & 63;
  const int wid = tid >> 6;
  const int l15 = lane & 15;
  const int l4 = lane >> 4;
  const int bid = xcd_swizzle(blockIdx.x, 1536);
  const int seg = bid / 512;
  const int inner = bid % 512;
  const int brow = (inner >> 3) << 7;
  const int bcol = (inner & 7) << 7;
  const int wm = (wid >> 1) << 6;
  const int wn = (wid & 1) << 6;

  const float* A = seg == 0 ? query : (seg == 1 ? key : value);
  const float* W = seg == 0 ? wq : (seg == 1 ? wk : wv);
  const float* bias = seg == 0 ? bq : (seg == 1 ? bk : bv);

  f32x4 acc[4][4] = {};
  gemm_core(A, W, brow, bcol, tid, wm, wn, l15, l4, Asm, Bsm, acc);

  const int r0 = brow + wm + l4 * 4;
  const int c0 = bcol + wn + l15;
  if (seg < 2) {
    bf16* C = seg == 0 ? Qws : Kws;
    const float cs = seg == 0 ? qscale : 1.0f;
#pragma unroll
    for (int n = 0; n < 4; ++n) {
      const float bvv = bias[c0 + n * 16];
#pragma unroll
      for (int m = 0; m < 4; ++m)
#pragma unroll
        for (int r = 0; r < 4; ++r)
          C[(size_t)(r0 + m * 16 + r) * 1024 + (c0 + n * 16)] =
              (bf16)((acc[m][n][r] + bvv) * cs);
    }
  } else {
    // Vt[b*1024 + col][s] = V[row][col]; rows r=0..3 are s-consecutive.
#pragma unroll
    for (int n = 0; n < 4; ++n) {
      const float bvv = bias[c0 + n * 16];
      const int col = c0 + n * 16;
#pragma unroll
      for (int m = 0; m < 4; ++m) {
        const int row = r0 + m * 16;
        const int bq_ = row >> 11;
        const int srow = row & 2047;
        bf16x4 pk4;
#pragma unroll
        for (int r = 0; r < 4; ++r) pk4[r] = (bf16)(acc[m][n][r] + bvv);
        *reinterpret_cast<bf16x4*>(
            &Vt[(size_t)(bq_ * 1024 + col) * 2048 + srow]) = pk4;
      }
    }
  }
}

// Output projection GEMM (bf16 ctx @ fp32 wo^T + bo -> fp32 out).
__global__ __launch_bounds__(256, 2) void out_gemm_kernel(
    const bf16* __restrict__ A, const float* __restrict__ W,
    const float* __restrict__ bias, float* __restrict__ C) {
  __shared__ bf16 Asm[2][128 * 64];
  __shared__ bf16 Bsm[2][128 * 64];
  const int tid = threadIdx.x;
  const int lane = tid & 63;
  const int wid = tid >> 6;
  const int l15 = lane & 15;
  const int l4 = lane >> 4;
  const int bid = xcd_swizzle(blockIdx.x, 512);
  const int brow = (bid >> 3) << 7;
  const int bcol = (bid & 7) << 7;
  const int wm = (wid >> 1) << 6;
  const int wn = (wid & 1) << 6;

  f32x4 acc[4][4] = {};
  gemm_core(A, W, brow, bcol, tid, wm, wn, l15, l4, Asm, Bsm, acc);

  const int r0 = brow + wm + l4 * 4;
  const int c0 = bcol + wn + l15;
#pragma unroll
  for (int n = 0; n < 4; ++n) {
    const float bvv = bias[c0 + n * 16];
#pragma unroll
    for (int m = 0; m < 4; ++m)
#pragma unroll
      for (int r = 0; r < 4; ++r)
        C[(size_t)(r0 + m * 16 + r) * 1024 + (c0 + n * 16)] =
            acc[m][n][r] + bvv;
  }
}

// ---------------- Flash attention: depth-3 pipeline, counted vmcnt ---------
// Block = (b, h, 128 q); 4 waves x 32 q. K/Vt tiles in 3 LDS buffers, staged
// 2 tiles ahead via global_load_lds; per tile: counted s_waitcnt vmcnt(20)
// (forces exactly stage(t); keeps stage(t+1,t+2)+2 mask sets in flight) +
// RAW s_barrier (no implicit drain - this was the r5..r9 ~205us wall).
// Mask double-buffered 2 tiles ahead in named reg sets mA/mB (loop unrolled
// x2). pi-permuted K (swap k-bits 2,3 in source row) keeps P lane-local for
// PV; mask*log2e is the QK MFMA C-init; Q pre-scaled by log2e/8; fixed-shift
// softmax (exact: |scores| << 88).
__global__ __launch_bounds__(256, 2) void attn_kernel(
    const bf16* __restrict__ Q, const bf16* __restrict__ Kt,
    const bf16* __restrict__ Vt, const float* __restrict__ mask,
    bf16* __restrict__ ctx) {
  __shared__ bf16 Ksm[3][64 * 64];
  __shared__ bf16 Vsm[3][64 * 64];
  const int lid = xcd_swizzle(blockIdx.x, 1024);
  const int h = lid & 15;
  const int qb = (lid >> 4) & 15;
  const int b = lid >> 8;
  const int tid = threadIdx.x;
  const int lane = tid & 63;
  const int wid = tid >> 6;
  const int l31 = lane & 31;
  const int h5 = lane >> 5;
  const int qbase = qb * 128 + wid * 32;

  // Q B-frags: qf[c] = Q[qbase+l31][16c + 8h5 + j] (pre-scaled by log2e/8)
  bf16x8 qf[4];
#pragma unroll
  for (int c = 0; c < 4; ++c)
    qf[c] = *reinterpret_cast<const bf16x8*>(
        &Q[(size_t)(b * 2048 + qbase + l31) * 1024 + h * 64 + c * 16 + h5 * 8]);

  f32x16 o[2] = {};  // D rows q=(reg&3)+8*(reg>>2)+4h5, col dsub*32+l31
  float lrow = 0.f;
  const float LOG2E = 1.44269504088896f;

  const bf16* Kb = Kt + (size_t)b * 2048 * 1024 + h * 64;
  const bf16* Vb = Vt + (size_t)(b * 16 + h) * 64 * 2048;

  // Staging pointers. K source row = pi(dest row) = swap bits 2,3.
  const int ca = tid, cb = 256 + tid;
  const int ra_ = ca >> 3, la = (ca & 7) ^ (ra_ & 7);
  const int rb_ = cb >> 3, lb = (cb & 7) ^ (rb_ & 7);
  const int pra = (ra_ & 51) | ((ra_ & 4) << 1) | ((ra_ & 8) >> 1);
  const int prb = (rb_ & 51) | ((rb_ & 4) << 1) | ((rb_ & 8) >> 1);
  const bf16* kga = Kb + (size_t)pra * 1024 + la * 8;
  const bf16* kgb = Kb + (size_t)prb * 1024 + lb * 8;
  const bf16* vga = Vb + (size_t)ra_ * 2048 + la * 8;
  const bf16* vgb = Vb + (size_t)rb_ * 2048 + lb * 8;
  const float* mg = mask + (size_t)b * 2048 * 2048 +
                    (size_t)(qbase + l31) * 2048 + h5 * 8;

  auto stage = [&](int p) {  // 4 vmem ops
    gload_lds16(kga, &Ksm[p][tid * 8]);
    gload_lds16(kgb, &Ksm[p][2048 + tid * 8]);
    gload_lds16(vga, &Vsm[p][tid * 8]);
    gload_lds16(vgb, &Vsm[p][2048 + tid * 8]);
    kga += 64 * 1024; kgb += 64 * 1024;
    vga += 64; vgb += 64;
  };
  f32x4 mA[2][4], mB[2][4];  // two named mask sets (2 tiles ahead)
  auto load_mask = [&](f32x4(&mr)[2][4]) {  // 8 vmem ops
#pragma unroll
    for (int s = 0; s < 2; ++s)
#pragma unroll
      for (int g = 0; g < 4; ++g)
        mr[s][g] = *reinterpret_cast<const f32x4*>(
            mg + s * 32 + (g >> 1) * 16 + (g & 1) * 4);
    mg += 64;
  };

  auto tile_compute = [&](int p, f32x4(&mr)[2][4]) {
    // sf init = mask * log2e (C-operand of the QK MFMA), pi-mapped cols.
    f32x16 sf[2];
#pragma unroll
    for (int s = 0; s < 2; ++s)
#pragma unroll
      for (int g = 0; g < 4; ++g)
#pragma unroll
        for (int r = 0; r < 4; ++r) sf[s][g * 4 + r] = mr[s][g][r] * LOG2E;

    __builtin_amdgcn_s_setprio(1);
#pragma unroll
    for (int s = 0; s < 2; ++s) {
#pragma unroll
      for (int c = 0; c < 4; ++c) {
        const int row = s * 32 + l31;
        const int slot = (2 * c + h5) ^ (row & 7);
        const bf16x8 kf =
            *reinterpret_cast<const bf16x8*>(&Ksm[p][row * 64 + slot * 8]);
        sf[s] = MFMA32(kf, qf[c], sf[s]);
      }
    }
    __builtin_amdgcn_s_setprio(0);

    // P = exp2(sf) -> bf16 pairs (lane-local; pi made them PV-frag-ordered)
    unsigned pk[2][4][2];
#pragma unroll
    for (int s = 0; s < 2; ++s) {
#pragma unroll
      for (int g = 0; g < 4; ++g) {
        const float p0 = __builtin_exp2f(sf[s][g * 4 + 0]);
        const float p1 = __builtin_exp2f(sf[s][g * 4 + 1]);
        const float p2 = __builtin_exp2f(sf[s][g * 4 + 2]);
        const float p3 = __builtin_exp2f(sf[s][g * 4 + 3]);
        lrow += (p0 + p1) + (p2 + p3);
        pk[s][g][0] = pack2bf(p0, p1);
        pk[s][g][1] = pack2bf(p2, p3);
      }
    }

    // PV: chunk c's A-frag = 4 lane-local u32s (compile-time indices).
    __builtin_amdgcn_s_setprio(1);
#pragma unroll
    for (int c = 0; c < 4; ++c) {
      const int s = c >> 1;
      const int g0 = 2 * (c & 1);
      const u32x4 uu = {pk[s][g0][0], pk[s][g0][1], pk[s][g0 + 1][0],
                        pk[s][g0 + 1][1]};
      const bf16x8 pa = __builtin_bit_cast(bf16x8, uu);
#pragma unroll
      for (int dsub = 0; dsub < 2; ++dsub) {
        const int row = dsub * 32 + l31;
        const int slot = (2 * c + h5) ^ (row & 7);
        const bf16x8 vf =
            *reinterpret_cast<const bf16x8*>(&Vsm[p][row * 64 + slot * 8]);
        o[dsub] = MFMA32(pa, vf, o[dsub]);
      }
    }
    __builtin_amdgcn_s_setprio(0);
  };

  // Prologue: buffers 0,1 + mask tiles 0,1. (24 vmem ops)
  stage(0);
  stage(1);
  load_mask(mA);
  load_mask(mB);

  int p = 0;  // buffer of (even) tile t
  for (int t = 0; t < 32; t += 2) {
    const int p1 = (p + 1 == 3) ? 0 : p + 1;
    const int p2 = (p + 2 >= 3) ? p - 1 : p + 2;
    // ---- even tile t (buffer p, mask mA) ----
    asm volatile("s_waitcnt vmcnt(20)" ::: "memory");
    __builtin_amdgcn_s_barrier();
    __builtin_amdgcn_sched_barrier(0);
    if (t + 2 < 32) stage(p2);
    tile_compute(p, mA);
    if (t + 2 < 32) load_mask(mA);
    // ---- odd tile t+1 (buffer p1, mask mB) ----
    asm volatile("s_waitcnt vmcnt(20)" ::: "memory");
    __builtin_amdgcn_s_barrier();
    __builtin_amdgcn_sched_barrier(0);
    if (t + 3 < 32) stage(p);  // (t+3)%3 == p; overwrites consumed buffer
    tile_compute(p1, mB);
    if (t + 3 < 32) load_mask(mB);
    p = p2;
  }

  // Partner lane (l^32) holds the other half of each row's sum.
  lrow += __shfl_xor(lrow, 32, 64);
  const float linv = __builtin_amdgcn_rcpf(lrow);
#pragma unroll
  for (int reg = 0; reg < 16; ++reg) {
    const int qr = (reg & 3) + 8 * (reg >> 2) + 4 * h5;
    const float li = __shfl(linv, qr, 64);
    const int q = qbase + qr;
#pragma unroll
    for (int dsub = 0; dsub < 2; ++dsub) {
      ctx[(size_t)(b * 2048 + q) * 1024 + h * 64 + dsub * 32 + l31] =
          (bf16)(o[dsub][reg] * li);
    }
  }
}

extern "C" void kernel_launch(void* const* d_in, const int* in_sizes, int n_in,
                              void* d_out, int out_size, void* d_ws,
                              size_t ws_size, hipStream_t stream) {
  const float* key = (const float*)d_in[0];
  const float* query = (const float*)d_in[1];
  const float* value = (const float*)d_in[2];
  const float* mask = (const float*)d_in[3];
  const float* wq = (const float*)d_in[4];
  const float* bq = (const float*)d_in[5];
  const float* wk = (const float*)d_in[6];
  const float* bk = (const float*)d_in[7];
  const float* wv = (const float*)d_in[8];
  const float* bv = (const float*)d_in[9];
  const float* wo = (const float*)d_in[10];
  const float* bo = (const float*)d_in[11];
  float* out = (float*)d_out;

  const size_t NBSH = (size_t)4 * 2048 * 1024;
  bf16* Qws = (bf16*)d_ws;   // Q (pre-scaled by log2e/8), later ctx in place
  bf16* Kws = Qws + NBSH;
  bf16* Vt = Kws + NBSH;     // total ws use: 50.3 MB

  const dim3 blk(256);
  qkv_gemm_kernel<<<1536, blk, 0, stream>>>(query, key, value, wq, wk, wv, bq,
                                            bk, bv, Qws, Kws, Vt,
                                            0.18033688011112f);
  attn_kernel<<<1024, blk, 0, stream>>>(Qws, Kws, Vt, mask, Qws);
  out_gemm_kernel<<<512, blk, 0, stream>>>(Qws, wo, bo, out);
}